// Round 13
// baseline (116.851 us; speedup 1.0000x reference)
//
#include <hip/hip_runtime.h>
#include <math.h>

#define NEXP 64
#define TOPK 8
#define TTILE 256          // tokens per tile
#define PITCH 65           // scalar LDS pitch: 2-way banks everywhere (free)
#define NPROD 4            // producer waves; waves 4-7 consume
#define BLKT 512
#define GRID 256           // 1 block/CU; 2048 tiles -> 8 per block exactly

typedef float v4 __attribute__((ext_vector_type(4)));

__global__ __launch_bounds__(BLKT) void router_kernel(
    const float* __restrict__ logits,
    float* __restrict__ out_logits,
    float* __restrict__ out_rw,
    float* __restrict__ out_tw,
    float* __restrict__ out_ti,
    float* __restrict__ out_hist,
    int nT)
{
    __shared__ float lds[2][TTILE * PITCH];   // 133.1 KB double-buffered tiles
    __shared__ float srow[2][TTILE];          // 1/ssum per token
    __shared__ float shist[NEXP];

    const int tid  = threadIdx.x;
    const int wid  = tid >> 6;
    const int l    = tid & 63;
    const bool prod = wid < NPROD;
    if (tid < NEXP) shist[tid] = 0.0f;

    const int G = gridDim.x;
    int tb = blockIdx.x;
    v4 regs[16];

    // ---- prologue: producers load tile tb and scatter -> LDS[0] (no pass) ----
    if (prod && tb < nT) {
        const v4* g = (const v4*)logits + (long)tb * (TTILE * NEXP / 4);
        #pragma unroll
        for (int k = 0; k < 16; ++k)
            regs[k] = __builtin_nontemporal_load(&g[(wid << 6) + l + (k << 8)]);
        #pragma unroll
        for (int k = 0; k < 16; ++k) {
            int i = (wid << 6) + l + (k << 8);
            v4 v = regs[k];
            int r = i >> 4, c4 = (i & 15) << 2;
            float* b = &lds[0][r * PITCH + c4];
            b[0] = v.x; b[1] = v.y; b[2] = v.z; b[3] = v.w;
        }
    }
    __syncthreads();

    int it = 0;
    for (; tb < nT; ++it, tb += G) {
        const int cur = it & 1;
        const int nxt = cur ^ 1;
        const int tb_next = tb + G;
        const bool hasNext = tb_next < nT;

        if (prod) {
            // (1) issue next tile's loads: in flight under everything below
            if (hasNext) {
                const v4* g = (const v4*)logits + (long)tb_next * (TTILE * NEXP / 4);
                #pragma unroll
                for (int k = 0; k < 16; ++k)
                    regs[k] = __builtin_nontemporal_load(&g[(wid << 6) + l + (k << 8)]);
            }
            // (2) rw-write of PREVIOUS tile from LDS[nxt] (exp) + srow[nxt]
            if (it > 0) {
                v4* grw = (v4*)out_rw + (long)(tb - G) * (TTILE * NEXP / 4);
                #pragma unroll
                for (int k = 0; k < 16; ++k) {
                    int i = (wid << 6) + l + (k << 8);
                    int r = i >> 4, c4 = (i & 15) << 2;
                    float si = srow[nxt][r];
                    const float* b = &lds[nxt][r * PITCH + c4];
                    v4 o = { b[0] * si, b[1] * si, b[2] * si, b[3] * si };
                    grw[i] = o;
                }
            }
            // (3) scatter next tile into LDS[nxt].
            // Same wave covers the SAME rows it rw-read in (2): per-wave
            // in-order DS guarantees read-before-overwrite. No extra barrier.
            if (hasNext) {
                #pragma unroll
                for (int k = 0; k < 16; ++k) {
                    int i = (wid << 6) + l + (k << 8);
                    v4 v = regs[k];
                    int r = i >> 4, c4 = (i & 15) << 2;
                    float* b = &lds[nxt][r * PITCH + c4];
                    b[0] = v.x; b[1] = v.y; b[2] = v.z; b[3] = v.w;
                }
            }
        } else {
            const int cw = wid - NPROD;            // consumer wave 0..3
            const int subBase = cw << 10;          // v4 offset of this wave's 64-token sub-block

            // (a) pass-through of tile t: read RAW rows from LDS[cur], store
            //     coalesced. Program-order precedes sweep's exp overwrite.
            v4* gp = (v4*)out_logits + (long)tb * (TTILE * NEXP / 4) + subBase;
            #pragma unroll
            for (int k = 0; k < 16; ++k) {
                int il = l + (k << 6);             // 0..1023 within sub-block
                int r  = (cw << 6) + (il >> 4);    // tile row
                int c4 = (il & 15) << 2;
                const float* b = &lds[cur][r * PITCH + c4];
                v4 v = { b[0], b[1], b[2], b[3] };
                gp[il] = v;
            }

            // (b) sweep own token: top-8 insert + exp in place + sum
            const int t = (cw << 6) + l;
            float* __restrict__ row = &lds[cur][t * PITCH];
            float vals[TOPK], ids[TOPK];
            #pragma unroll
            for (int j = 0; j < TOPK; ++j) { vals[j] = -INFINITY; ids[j] = 0.0f; }
            float ssum = 0.0f;

            #pragma unroll 8
            for (int e = 0; e < NEXP; ++e) {
                float x  = row[e];
                float ev = __expf(x);
                ssum += ev;
                row[e] = ev;               // overwrite raw logits with exp(x)
                float fe = (float)e;
                bool c[TOPK];
                #pragma unroll
                for (int j = 0; j < TOPK; ++j) c[j] = x > vals[j];
                #pragma unroll
                for (int j = TOPK - 1; j >= 1; --j) {
                    ids[j]  = c[j] ? (c[j - 1] ? ids[j - 1] : fe) : ids[j];
                    vals[j] = __builtin_amdgcn_fmed3f(x, vals[j - 1], vals[j]);
                }
                ids[0]  = c[0] ? fe : ids[0];
                vals[0] = fmaxf(vals[0], x);
            }
            const float sinv = 1.0f / ssum;
            srow[cur][t] = sinv;

            // (c) top-k weights from registers (denominator cancels)
            float ew[TOPK];
            float tsum = 0.0f;
            #pragma unroll
            for (int j = 0; j < TOPK; ++j) { ew[j] = __expf(vals[j]); tsum += ew[j]; }
            const float tinv = 1.0f / tsum;

            const long tok = (long)tb * TTILE + t;
            v4* twp = (v4*)out_tw + tok * 2;
            v4* tip = (v4*)out_ti + tok * 2;
            v4 w0 = { ew[0] * tinv, ew[1] * tinv, ew[2] * tinv, ew[3] * tinv };
            v4 w1 = { ew[4] * tinv, ew[5] * tinv, ew[6] * tinv, ew[7] * tinv };
            v4 i0 = { ids[0], ids[1], ids[2], ids[3] };
            v4 i1 = { ids[4], ids[5], ids[6], ids[7] };
            twp[0] = w0; twp[1] = w1;
            tip[0] = i0; tip[1] = i1;

            #pragma unroll
            for (int j = 0; j < TOPK; ++j)
                atomicAdd(&shist[(int)ids[j]], 1.0f);
        }
        __syncthreads();   // tile swept + staged; srow[cur] published
    }

    // ---- epilogue: rw-write of the final swept tile ----
    if (prod && it > 0) {
        const int lastpar = (it - 1) & 1;
        v4* grw = (v4*)out_rw + (long)(tb - G) * (TTILE * NEXP / 4);
        #pragma unroll
        for (int k = 0; k < 16; ++k) {
            int i = (wid << 6) + l + (k << 8);
            int r = i >> 4, c4 = (i & 15) << 2;
            float si = srow[lastpar][r];
            const float* b = &lds[lastpar][r * PITCH + c4];
            v4 o = { b[0] * si, b[1] * si, b[2] * si, b[3] * si };
            grw[i] = o;
        }
    }
    // consumers' last shist adds are before the final in-loop barrier,
    // which producer wave 0 also crossed -> flush is ordered correctly.
    if (tid < NEXP) atomicAdd(&out_hist[tid], shist[tid]);
}

extern "C" void kernel_launch(void* const* d_in, const int* in_sizes, int n_in,
                              void* d_out, int out_size, void* d_ws, size_t ws_size,
                              hipStream_t stream) {
    const float* logits = (const float*)d_in[0];
    const long T = (long)in_sizes[0] / NEXP;

    float* out      = (float*)d_out;
    float* o_logits = out;
    float* o_rw     = out + T * NEXP;
    float* o_tw     = out + 2 * T * NEXP;
    float* o_ti     = o_tw + T * TOPK;
    float* o_hist   = o_ti + T * TOPK;

    (void)hipMemsetAsync(o_hist, 0, NEXP * sizeof(float), stream);

    const int nT   = (int)(T / TTILE);     // 2048 tiles
    const int grid = nT < GRID ? nT : GRID;
    router_kernel<<<grid, BLKT, 0, stream>>>(logits, o_logits, o_rw, o_tw, o_ti,
                                             o_hist, nT);
}

// Round 14
// 106.876 us; speedup vs baseline: 1.0933x; 1.0933x over previous
//
#include <hip/hip_runtime.h>
#include <math.h>

#define NEXP 64
#define TOPK 8
#define TTILE 128          // tokens per tile
#define PITCH 65           // scalar LDS pitch: 2-way banks everywhere (free)
#define NPROD 2            // producer waves; waves 2-3 consume
#define BLKT 256
#define GRID 512           // 2 blocks/CU; 4096 tiles -> 8 per block exactly

typedef float v4 __attribute__((ext_vector_type(4)));

__global__ __launch_bounds__(BLKT) void router_kernel(
    const float* __restrict__ logits,
    float* __restrict__ out_logits,
    float* __restrict__ out_rw,
    float* __restrict__ out_tw,
    float* __restrict__ out_ti,
    float* __restrict__ out_hist,
    int nT)
{
    __shared__ float lds[2][TTILE * PITCH];   // 66.6 KB double-buffered tiles
    __shared__ float srow[2][TTILE];          // 1/ssum per token
    __shared__ float shist[NEXP];

    const int tid  = threadIdx.x;
    const int wid  = tid >> 6;
    const int l    = tid & 63;
    const bool prod = wid < NPROD;
    if (tid < NEXP) shist[tid] = 0.0f;

    const int G = gridDim.x;
    int tb = blockIdx.x;
    v4 regs[16];

    // ---- prologue: producers load tile tb, pass-store, scatter -> LDS[0] ----
    if (prod && tb < nT) {
        const long base = (long)tb * (TTILE * NEXP / 4);
        const v4* g = (const v4*)logits + base;
        #pragma unroll
        for (int k = 0; k < 16; ++k)
            regs[k] = __builtin_nontemporal_load(&g[(wid << 6) + l + (k << 7)]);
        v4* gp = (v4*)out_logits + base;
        #pragma unroll
        for (int k = 0; k < 16; ++k) {
            int i = (wid << 6) + l + (k << 7);
            v4 v = regs[k];
            gp[i] = v;
            int r = i >> 4, c4 = (i & 15) << 2;
            float* b = &lds[0][r * PITCH + c4];
            b[0] = v.x; b[1] = v.y; b[2] = v.z; b[3] = v.w;
        }
    }
    __syncthreads();

    int it = 0;
    for (; tb < nT; ++it, tb += G) {
        const int cur = it & 1;
        const int nxt = cur ^ 1;
        const int tb_next = tb + G;

        if (prod) {
            // (1) issue next tile's loads first: in flight under everything below
            if (tb_next < nT) {
                const v4* g = (const v4*)logits + (long)tb_next * (TTILE * NEXP / 4);
                #pragma unroll
                for (int k = 0; k < 16; ++k)
                    regs[k] = __builtin_nontemporal_load(&g[(wid << 6) + l + (k << 7)]);
            }
            // (2) rw-write of PREVIOUS tile (exp in LDS[nxt], sinv in srow[nxt])
            if (it > 0) {
                v4* grw = (v4*)out_rw + (long)(tb - G) * (TTILE * NEXP / 4);
                #pragma unroll
                for (int k = 0; k < 16; ++k) {
                    int i = (wid << 6) + l + (k << 7);
                    int r = i >> 4, c4 = (i & 15) << 2;
                    float si = srow[nxt][r];
                    const float* b = &lds[nxt][r * PITCH + c4];
                    v4 o = { b[0] * si, b[1] * si, b[2] * si, b[3] * si };
                    grw[i] = o;
                }
            }
            // (3) pass-store + scatter next tile into LDS[nxt] (after rw reads it;
            //     same wave covers the same rows -> per-wave DS order is safe)
            if (tb_next < nT) {
                v4* gp = (v4*)out_logits + (long)tb_next * (TTILE * NEXP / 4);
                #pragma unroll
                for (int k = 0; k < 16; ++k) {
                    int i = (wid << 6) + l + (k << 7);
                    v4 v = regs[k];
                    gp[i] = v;
                    int r = i >> 4, c4 = (i & 15) << 2;
                    float* b = &lds[nxt][r * PITCH + c4];
                    b[0] = v.x; b[1] = v.y; b[2] = v.z; b[3] = v.w;
                }
            }
        } else {
            // ---- consumer: sweep own token in LDS[cur] ----
            const int t = ((wid - NPROD) << 6) + l;
            float* __restrict__ row = &lds[cur][t * PITCH];
            float vals[TOPK], ids[TOPK];
            #pragma unroll
            for (int j = 0; j < TOPK; ++j) { vals[j] = -INFINITY; ids[j] = 0.0f; }
            float ssum = 0.0f;

            #pragma unroll 8
            for (int e = 0; e < NEXP; ++e) {
                float x  = row[e];
                float ev = __expf(x);
                ssum += ev;
                row[e] = ev;               // overwrite raw logits with exp(x)
                float fe = (float)e;
                bool c[TOPK];
                #pragma unroll
                for (int j = 0; j < TOPK; ++j) c[j] = x > vals[j];
                #pragma unroll
                for (int j = TOPK - 1; j >= 1; --j) {
                    ids[j]  = c[j] ? (c[j - 1] ? ids[j - 1] : fe) : ids[j];
                    vals[j] = __builtin_amdgcn_fmed3f(x, vals[j - 1], vals[j]);
                }
                ids[0]  = c[0] ? fe : ids[0];
                vals[0] = fmaxf(vals[0], x);
            }
            const float sinv = 1.0f / ssum;
            srow[cur][t] = sinv;

            float ew[TOPK];
            float tsum = 0.0f;
            #pragma unroll
            for (int j = 0; j < TOPK; ++j) { ew[j] = __expf(vals[j]); tsum += ew[j]; }
            const float tinv = 1.0f / tsum;

            const long tok = (long)tb * TTILE + t;
            v4* twp = (v4*)out_tw + tok * 2;
            v4* tip = (v4*)out_ti + tok * 2;
            v4 w0 = { ew[0] * tinv, ew[1] * tinv, ew[2] * tinv, ew[3] * tinv };
            v4 w1 = { ew[4] * tinv, ew[5] * tinv, ew[6] * tinv, ew[7] * tinv };
            v4 i0 = { ids[0], ids[1], ids[2], ids[3] };
            v4 i1 = { ids[4], ids[5], ids[6], ids[7] };
            twp[0] = w0; twp[1] = w1;
            tip[0] = i0; tip[1] = i1;

            #pragma unroll
            for (int j = 0; j < TOPK; ++j)
                atomicAdd(&shist[(int)ids[j]], 1.0f);
        }
        __syncthreads();   // tile swept; next tile staged; srow[cur] published
    }

    // ---- epilogue: rw-write of the final swept tile ----
    if (prod && it > 0) {
        const int lastpar = (it - 1) & 1;
        v4* grw = (v4*)out_rw + (long)(tb - G) * (TTILE * NEXP / 4);
        #pragma unroll
        for (int k = 0; k < 16; ++k) {
            int i = (wid << 6) + l + (k << 7);
            int r = i >> 4, c4 = (i & 15) << 2;
            float si = srow[lastpar][r];
            const float* b = &lds[lastpar][r * PITCH + c4];
            v4 o = { b[0] * si, b[1] * si, b[2] * si, b[3] * si };
            grw[i] = o;
        }
    }
    __syncthreads();
    if (tid < NEXP) atomicAdd(&out_hist[tid], shist[tid]);
}

extern "C" void kernel_launch(void* const* d_in, const int* in_sizes, int n_in,
                              void* d_out, int out_size, void* d_ws, size_t ws_size,
                              hipStream_t stream) {
    const float* logits = (const float*)d_in[0];
    const long T = (long)in_sizes[0] / NEXP;

    float* out      = (float*)d_out;
    float* o_logits = out;
    float* o_rw     = out + T * NEXP;
    float* o_tw     = out + 2 * T * NEXP;
    float* o_ti     = o_tw + T * TOPK;
    float* o_hist   = o_ti + T * TOPK;

    (void)hipMemsetAsync(o_hist, 0, NEXP * sizeof(float), stream);

    const int nT   = (int)(T / TTILE);     // 4096 tiles
    const int grid = nT < GRID ? nT : GRID;
    router_kernel<<<grid, BLKT, 0, stream>>>(logits, o_logits, o_rw, o_tw, o_ti,
                                             o_hist, nT);
}

// Round 15
// 88.759 us; speedup vs baseline: 1.3165x; 1.2041x over previous
//
#include <hip/hip_runtime.h>
#include <math.h>

#define NEXP 64
#define TOPK 8
#define TTILE 256          // tokens per tile
#define PITCH 65           // scalar LDS pitch: 2-way banks everywhere (free)
#define NPROD 4            // producer waves; waves 4-7 consume
#define BLKT 512
#define GRID 256           // 1 block/CU; 2048 tiles -> 8 per block exactly

typedef float v4 __attribute__((ext_vector_type(4)));

// Barrier that drains ONLY the LDS queue (lgkmcnt), leaving global stores
// in flight across tiles. __syncthreads would force vmcnt(0): a full
// store-queue drain per tile that nothing in this kernel needs.
#define FAST_BAR() do {                                       \
    __builtin_amdgcn_sched_barrier(0);                        \
    asm volatile("s_waitcnt lgkmcnt(0)" ::: "memory");        \
    __builtin_amdgcn_s_barrier();                             \
    __builtin_amdgcn_sched_barrier(0);                        \
} while (0)

__global__ __launch_bounds__(BLKT) void router_kernel(
    const float* __restrict__ logits,
    float* __restrict__ out_logits,
    float* __restrict__ out_rw,
    float* __restrict__ out_tw,
    float* __restrict__ out_ti,
    float* __restrict__ out_hist,
    int nT)
{
    __shared__ float lds[2][TTILE * PITCH];   // 133.1 KB double-buffered tiles
    __shared__ float srow[2][TTILE];          // 1/ssum per token
    __shared__ float shist[NEXP];

    const int tid  = threadIdx.x;
    const int wid  = tid >> 6;
    const int l    = tid & 63;
    const bool prod = wid < NPROD;
    if (tid < NEXP) shist[tid] = 0.0f;

    const int G = gridDim.x;
    int tb = blockIdx.x;
    v4 regs[16];

    // ---- prologue: producers load tile tb, pass-store, scatter -> LDS[0] ----
    if (prod && tb < nT) {
        const long base = (long)tb * (TTILE * NEXP / 4);
        const v4* g = (const v4*)logits + base;
        #pragma unroll
        for (int k = 0; k < 16; ++k)
            regs[k] = __builtin_nontemporal_load(&g[(wid << 6) + l + (k << 8)]);
        v4* gp = (v4*)out_logits + base;
        #pragma unroll
        for (int k = 0; k < 16; ++k) {
            int i = (wid << 6) + l + (k << 8);
            v4 v = regs[k];
            gp[i] = v;
            int r = i >> 4, c4 = (i & 15) << 2;
            float* b = &lds[0][r * PITCH + c4];
            b[0] = v.x; b[1] = v.y; b[2] = v.z; b[3] = v.w;
        }
    }
    FAST_BAR();

    int it = 0;
    for (; tb < nT; ++it, tb += G) {
        const int cur = it & 1;
        const int nxt = cur ^ 1;
        const int tb_next = tb + G;

        if (prod) {
            // (1) issue next tile's loads first: in flight under everything below
            if (tb_next < nT) {
                const v4* g = (const v4*)logits + (long)tb_next * (TTILE * NEXP / 4);
                #pragma unroll
                for (int k = 0; k < 16; ++k)
                    regs[k] = __builtin_nontemporal_load(&g[(wid << 6) + l + (k << 8)]);
            }
            // (2) rw-write of PREVIOUS tile (exp in LDS[nxt], sinv in srow[nxt])
            if (it > 0) {
                v4* grw = (v4*)out_rw + (long)(tb - G) * (TTILE * NEXP / 4);
                #pragma unroll
                for (int k = 0; k < 16; ++k) {
                    int i = (wid << 6) + l + (k << 8);
                    int r = i >> 4, c4 = (i & 15) << 2;
                    float si = srow[nxt][r];
                    const float* b = &lds[nxt][r * PITCH + c4];
                    v4 o = { b[0] * si, b[1] * si, b[2] * si, b[3] * si };
                    grw[i] = o;
                }
            }
            // (3) pass-store + scatter next tile into LDS[nxt] (after rw reads it;
            //     same wave covers the same rows -> per-wave DS order is safe)
            if (tb_next < nT) {
                v4* gp = (v4*)out_logits + (long)tb_next * (TTILE * NEXP / 4);
                #pragma unroll
                for (int k = 0; k < 16; ++k) {
                    int i = (wid << 6) + l + (k << 8);
                    v4 v = regs[k];
                    gp[i] = v;
                    int r = i >> 4, c4 = (i & 15) << 2;
                    float* b = &lds[nxt][r * PITCH + c4];
                    b[0] = v.x; b[1] = v.y; b[2] = v.z; b[3] = v.w;
                }
            }
        } else {
            // ---- consumer: sweep own token in LDS[cur] ----
            const int t = ((wid - NPROD) << 6) + l;
            float* __restrict__ row = &lds[cur][t * PITCH];
            float vals[TOPK], ids[TOPK];
            #pragma unroll
            for (int j = 0; j < TOPK; ++j) { vals[j] = -INFINITY; ids[j] = 0.0f; }
            float ssum = 0.0f;

            #pragma unroll 8
            for (int e = 0; e < NEXP; ++e) {
                float x  = row[e];
                float ev = __expf(x);
                ssum += ev;
                row[e] = ev;               // overwrite raw logits with exp(x)
                float fe = (float)e;
                bool c[TOPK];
                #pragma unroll
                for (int j = 0; j < TOPK; ++j) c[j] = x > vals[j];
                #pragma unroll
                for (int j = TOPK - 1; j >= 1; --j) {
                    ids[j]  = c[j] ? (c[j - 1] ? ids[j - 1] : fe) : ids[j];
                    vals[j] = __builtin_amdgcn_fmed3f(x, vals[j - 1], vals[j]);
                }
                ids[0]  = c[0] ? fe : ids[0];
                vals[0] = fmaxf(vals[0], x);
            }
            const float sinv = 1.0f / ssum;
            srow[cur][t] = sinv;

            float ew[TOPK];
            float tsum = 0.0f;
            #pragma unroll
            for (int j = 0; j < TOPK; ++j) { ew[j] = __expf(vals[j]); tsum += ew[j]; }
            const float tinv = 1.0f / tsum;

            const long tok = (long)tb * TTILE + t;
            v4* twp = (v4*)out_tw + tok * 2;
            v4* tip = (v4*)out_ti + tok * 2;
            v4 w0 = { ew[0] * tinv, ew[1] * tinv, ew[2] * tinv, ew[3] * tinv };
            v4 w1 = { ew[4] * tinv, ew[5] * tinv, ew[6] * tinv, ew[7] * tinv };
            v4 i0 = { ids[0], ids[1], ids[2], ids[3] };
            v4 i1 = { ids[4], ids[5], ids[6], ids[7] };
            twp[0] = w0; twp[1] = w1;
            tip[0] = i0; tip[1] = i1;

            #pragma unroll
            for (int j = 0; j < TOPK; ++j)
                atomicAdd(&shist[(int)ids[j]], 1.0f);
        }
        FAST_BAR();        // LDS-only drain; global stores stay in flight
    }

    // ---- epilogue: rw-write of the final swept tile ----
    if (prod && it > 0) {
        const int lastpar = (it - 1) & 1;
        v4* grw = (v4*)out_rw + (long)(tb - G) * (TTILE * NEXP / 4);
        #pragma unroll
        for (int k = 0; k < 16; ++k) {
            int i = (wid << 6) + l + (k << 8);
            int r = i >> 4, c4 = (i & 15) << 2;
            float si = srow[lastpar][r];
            const float* b = &lds[lastpar][r * PITCH + c4];
            v4 o = { b[0] * si, b[1] * si, b[2] * si, b[3] * si };
            grw[i] = o;
        }
    }
    __syncthreads();
    if (tid < NEXP) atomicAdd(&out_hist[tid], shist[tid]);
}

extern "C" void kernel_launch(void* const* d_in, const int* in_sizes, int n_in,
                              void* d_out, int out_size, void* d_ws, size_t ws_size,
                              hipStream_t stream) {
    const float* logits = (const float*)d_in[0];
    const long T = (long)in_sizes[0] / NEXP;

    float* out      = (float*)d_out;
    float* o_logits = out;
    float* o_rw     = out + T * NEXP;
    float* o_tw     = out + 2 * T * NEXP;
    float* o_ti     = o_tw + T * TOPK;
    float* o_hist   = o_ti + T * TOPK;

    (void)hipMemsetAsync(o_hist, 0, NEXP * sizeof(float), stream);

    const int nT   = (int)(T / TTILE);     // 2048 tiles
    const int grid = nT < GRID ? nT : GRID;
    router_kernel<<<grid, BLKT, 0, stream>>>(logits, o_logits, o_rw, o_tw, o_ti,
                                             o_hist, nT);
}